// Round 10
// baseline (292.335 us; speedup 1.0000x reference)
//
#include <hip/hip_runtime.h>
#include <hip/hip_bf16.h>

#define N_NODES 50000
#define N_EDGES 800000
#define N_GRAPHS 64
#define FEAT 128
#define EMB 256
#define HID 512
#define VOCAB 512

#define BKT 64                                      // padded-CSR bucket width (deg ~Poisson(16), max ~38)

// ---- M-doubled GEMM geometry: 256-row x 128-col tiles ----
#define RB2 ((N_NODES + 255) / 256)                 // 196 row-blocks
#define RPX2 ((RB2 + 7) / 8)                        // 25 row-blocks per XCD

// ---- partition sort geometry ----
#define NPB 98                                      // coarse buckets: dst>>9 (512 nodes each)
#define BCAP 10240                                  // capacity per coarse bucket (mean 8163, +20 sigma safe)
#define PA_EDGES 4096                               // edges per phase-A block
#define PA_BLOCKS ((N_EDGES + PA_EDGES - 1) / PA_EDGES)  // 196
#define BC_STR 16                                   // bktcnt stride in ints (64B padding)

// ---- head split-K geometry ----
#define KC 4                                        // k-chunks for head_hc split
#define KCH (HID / KC)                              // 128 k per chunk
#define KO 4                                        // k-chunks for logits split
#define KOH (HID / KO)                              // 128 k per chunk

#define CONV_ELEMS (N_NODES * 32 + 256 * 256 + 512 * 512)  // 1,927,680
#define CONV_BLOCKS (CONV_ELEMS / 256)              // 7530

typedef __attribute__((ext_vector_type(4))) float floatx4;
typedef __attribute__((ext_vector_type(2))) float floatx2;
typedef unsigned int uint32;
typedef unsigned char uchar_t;

// u holds 4 fp8 e4m3; accumulate into a[0..3]
__device__ __forceinline__ void accf8(uint32 u, float* a) {
    floatx2 lo = __builtin_amdgcn_cvt_pk_f32_fp8(u, false);
    floatx2 hi = __builtin_amdgcn_cvt_pk_f32_fp8(u, true);
    a[0] += lo[0]; a[1] += lo[1]; a[2] += hi[0]; a[3] += hi[1];
}
__device__ __forceinline__ uchar_t f2f8(float v) {
    return (uchar_t)(__builtin_amdgcn_cvt_pk_fp8_f32(v, v, 0, false) & 0xff);
}
__device__ __forceinline__ uint32 pk4f8(float a, float b, float c, float d) {
    uint32 w = __builtin_amdgcn_cvt_pk_fp8_f32(a, b, 0, false);
    return __builtin_amdgcn_cvt_pk_fp8_f32(c, d, w, true);
}
__device__ __forceinline__ void async16(const void* g, void* l) {
    __builtin_amdgcn_global_load_lds(
        (const __attribute__((address_space(1))) void*)g,
        (__attribute__((address_space(3))) void*)l, 16, 0, 0);
}

// ---------------- prep: phase-A partition (LDS-binned, coalesced out) + fp8 converts ----------------
__global__ void prep_kernel(const int* __restrict__ edge, int* __restrict__ bktcnt,
                            int2* __restrict__ bktbuf,
                            const float* __restrict__ x,
                            const float* __restrict__ W01, const float* __restrict__ W11,
                            const float* __restrict__ W02, const float* __restrict__ W12,
                            uchar_t* __restrict__ xa8,
                            uchar_t* __restrict__ w1t8, uchar_t* __restrict__ w2t8) {
    if (blockIdx.x < PA_BLOCKS) {
        __shared__ int hist[NPB];
        __shared__ int excl[NPB];
        __shared__ int lpos[NPB];
        __shared__ int gbase[NPB];
        __shared__ int2 stage[PA_EDGES];
        const int t = threadIdx.x;
        const int e0 = blockIdx.x * PA_EDGES;
        const int ne = min(PA_EDGES, N_EDGES - e0);

        if (t < NPB) hist[t] = 0;
        __syncthreads();
        for (int s = t; s < ne; s += 256) {
            int d = edge[N_EDGES + e0 + s];
            atomicAdd(&hist[d >> 9], 1);
        }
        __syncthreads();
        if (t == 0) {
            int run = 0;
            for (int i = 0; i < NPB; ++i) { excl[i] = run; run += hist[i]; }
        }
        __syncthreads();
        if (t < NPB) {
            gbase[t] = atomicAdd(bktcnt + t * BC_STR, hist[t]);
            lpos[t] = excl[t];
        }
        __syncthreads();
        for (int s = t; s < ne; s += 256) {
            int src = edge[e0 + s];
            int d = edge[N_EDGES + e0 + s];
            int b = d >> 9;
            int lp = atomicAdd(&lpos[b], 1);
            stage[lp] = make_int2(src, d);
        }
        __syncthreads();
        for (int s = t; s < ne; s += 256) {
            int2 p = stage[s];
            int b = p.y >> 9;
            int g = gbase[b] + (s - excl[b]);
            if (g < BCAP) bktbuf[(size_t)b * BCAP + g] = p;
        }
    } else {
        int tid = (blockIdx.x - PA_BLOCKS) * 256 + threadIdx.x;
        if (tid < N_NODES * 32) {
            int row = tid >> 5, c = (tid & 31) * 4;
            float4 v = *(const float4*)(x + (size_t)row * FEAT + c);
            *(uint32*)(xa8 + (size_t)row * 256 + c) = pk4f8(v.x, v.y, v.z, v.w);
        } else if (tid < N_NODES * 32 + 256 * 256) {
            int t1 = tid - N_NODES * 32;
            int n = t1 >> 8, k = t1 & 255;
            float v = (k < 128) ? W01[(size_t)k * 256 + n] : W11[(size_t)(k - 128) * 256 + n];
            w1t8[t1] = f2f8(v);
        } else {
            int t2 = tid - N_NODES * 32 - 256 * 256;
            int n = t2 >> 9, k = t2 & 511;
            float v = (k < 256) ? W02[(size_t)k * 512 + n] : W12[(size_t)(k - 256) * 512 + n];
            w2t8[t2] = f2f8(v);
        }
    }
}

// ---------------- phase B: per-bucket L2-local CSR scatter + exact counts (512 thr) ----------------
__global__ __launch_bounds__(512) void bucket_kernel(const int* __restrict__ bktcnt,
                                                     const int2* __restrict__ bktbuf,
                                                     int* __restrict__ srcbuf,
                                                     int* __restrict__ cnt) {
    __shared__ int lcur[512];
    const int b = blockIdx.x;
    const int t = threadIdx.x;
    const int n0 = b << 9;
    const int nn = min(512, N_NODES - n0);
    const int ne = min(bktcnt[b * BC_STR], BCAP);

    lcur[t] = 0;
    __syncthreads();
    for (int s = t; s < ne; s += 512) {
        int2 p = bktbuf[(size_t)b * BCAP + s];
        int d = p.y & 511;
        int k = atomicAdd(&lcur[d], 1);
        if (k < BKT) srcbuf[((size_t)(n0 + d) << 6) + k] = p.x;
    }
    __syncthreads();
    if (t < nn) cnt[n0 + t] = lcur[t];
}

// ---------------- CSR gathers (padded buckets, stride 64) ----------------
// gather1: fp8 in/out on xa8[50000][256] (cols 0..127 = x fp8, 128..255 = agg1 fp8)
__global__ __launch_bounds__(256) void gather1_kernel(
    const int* __restrict__ cnt, const int* __restrict__ srcbuf,
    uchar_t* __restrict__ xa8)
{
    int node = blockIdx.x * 4 + (threadIdx.x >> 6);
    if (node >= N_NODES) return;
    int lane = threadIdx.x & 63;
    int grp = lane >> 3;
    int l8 = lane & 7;
    int c_ = cnt[node];
    float ri = 1.0f / (float)max(c_, 1);
    int beg = node << 6;
    int end = beg + min(c_, BKT);

    float a[16];
    #pragma unroll
    for (int k = 0; k < 16; ++k) a[k] = 0.f;

    int j = beg + grp;
    for (; j + 8 < end; j += 16) {
        int s0 = srcbuf[j];
        int s1 = srcbuf[j + 8];
        uint4 u0 = *(const uint4*)(xa8 + (size_t)s0 * 256 + l8 * 16);
        uint4 u1 = *(const uint4*)(xa8 + (size_t)s1 * 256 + l8 * 16);
        accf8(u0.x, a + 0); accf8(u0.y, a + 4); accf8(u0.z, a + 8); accf8(u0.w, a + 12);
        accf8(u1.x, a + 0); accf8(u1.y, a + 4); accf8(u1.z, a + 8); accf8(u1.w, a + 12);
    }
    for (; j < end; j += 8) {
        int s0 = srcbuf[j];
        uint4 u0 = *(const uint4*)(xa8 + (size_t)s0 * 256 + l8 * 16);
        accf8(u0.x, a + 0); accf8(u0.y, a + 4); accf8(u0.z, a + 8); accf8(u0.w, a + 12);
    }
    #pragma unroll
    for (int k = 0; k < 16; ++k) a[k] += __shfl_down(a[k], 32);
    #pragma unroll
    for (int k = 0; k < 16; ++k) a[k] += __shfl_down(a[k], 16);
    #pragma unroll
    for (int k = 0; k < 16; ++k) a[k] += __shfl_down(a[k], 8);
    if (grp == 0) {
        uint4 o;
        o.x = pk4f8(a[0] * ri,  a[1] * ri,  a[2] * ri,  a[3] * ri);
        o.y = pk4f8(a[4] * ri,  a[5] * ri,  a[6] * ri,  a[7] * ri);
        o.z = pk4f8(a[8] * ri,  a[9] * ri,  a[10] * ri, a[11] * ri);
        o.w = pk4f8(a[12] * ri, a[13] * ri, a[14] * ri, a[15] * ri);
        *(uint4*)(xa8 + (size_t)node * 256 + 128 + l8 * 16) = o;
    }
}

// gather2: fp8 in/out on h1a8[50000][512] (cols 0..255 = h1 fp8, 256..511 = agg2 fp8)
__global__ __launch_bounds__(256) void gather2_kernel(
    const int* __restrict__ cnt, const int* __restrict__ srcbuf,
    uchar_t* __restrict__ h1a8)
{
    int node = blockIdx.x * 4 + (threadIdx.x >> 6);
    if (node >= N_NODES) return;
    int lane = threadIdx.x & 63;
    int grp = lane >> 4;
    int l16 = lane & 15;
    int c_ = cnt[node];
    float ri = 1.0f / (float)max(c_, 1);
    int beg = node << 6;
    int end = beg + min(c_, BKT);

    float a[16];
    #pragma unroll
    for (int k = 0; k < 16; ++k) a[k] = 0.f;

    int j = beg + grp;
    for (; j + 4 < end; j += 8) {
        int s0 = srcbuf[j];
        int s1 = srcbuf[j + 4];
        uint4 u0 = *(const uint4*)(h1a8 + (size_t)s0 * 512 + l16 * 16);
        uint4 u1 = *(const uint4*)(h1a8 + (size_t)s1 * 512 + l16 * 16);
        accf8(u0.x, a + 0); accf8(u0.y, a + 4); accf8(u0.z, a + 8); accf8(u0.w, a + 12);
        accf8(u1.x, a + 0); accf8(u1.y, a + 4); accf8(u1.z, a + 8); accf8(u1.w, a + 12);
    }
    for (; j < end; j += 4) {
        int s0 = srcbuf[j];
        uint4 u0 = *(const uint4*)(h1a8 + (size_t)s0 * 512 + l16 * 16);
        accf8(u0.x, a + 0); accf8(u0.y, a + 4); accf8(u0.z, a + 8); accf8(u0.w, a + 12);
    }
    #pragma unroll
    for (int k = 0; k < 16; ++k) a[k] += __shfl_down(a[k], 32);
    #pragma unroll
    for (int k = 0; k < 16; ++k) a[k] += __shfl_down(a[k], 16);
    if (grp == 0) {
        uint4 o;
        o.x = pk4f8(a[0] * ri,  a[1] * ri,  a[2] * ri,  a[3] * ri);
        o.y = pk4f8(a[4] * ri,  a[5] * ri,  a[6] * ri,  a[7] * ri);
        o.z = pk4f8(a[8] * ri,  a[9] * ri,  a[10] * ri, a[11] * ri);
        o.w = pk4f8(a[12] * ri, a[13] * ri, a[14] * ri, a[15] * ri);
        *(uint4*)(h1a8 + (size_t)node * 512 + 256 + l16 * 16) = o;
    }
}

// ---------------- fp8 MFMA GEMM (256x128 tile = 2 row-subtiles sharing B, BK=128) ----------------
// Short-K amortization: 128 MFMA per barrier pair (vs 64), B staged/read once for both subtiles.
// POOL=false: relu(acc+bias) -> fp8 to outf8 (row stride OUTSTR) at col0.
// POOL=true : pool rows by batch[] into psum.
template<int KTOT, int OUTSTR, bool POOL, int COLS>
__global__ __launch_bounds__(256) void mfma_gemm_f8(
    const uchar_t* __restrict__ A, const uchar_t* __restrict__ Bt,
    const float* __restrict__ bias, uchar_t* __restrict__ outf8,
    float* __restrict__ psum, const int* __restrict__ batch)
{
    __shared__ uchar_t As[2][16384];    // 2 x (128 rows x 128 B)
    __shared__ uchar_t Bs[16384];
    __shared__ float pool2[8 * 128];

    const int id = blockIdx.x;
    const int xcd = id & 7;
    const int s_ = id >> 3;
    const int col = s_ & (COLS - 1);
    const int rloc = s_ / COLS;
    const int rowblk = xcd * RPX2 + rloc;
    if (rowblk >= RB2) return;

    const int tid = threadIdx.x;
    const int lane = tid & 63;
    const int wave = tid >> 6;
    const int quad = lane >> 4;
    const int l16 = lane & 15;
    const int m0w = (wave & 1) * 64;
    const int n0w = (wave >> 1) * 64;
    const int row0 = rowblk * 256;
    const int col0 = col * 128;
    const int Mm1 = N_NODES - 1;

    int st_r[4], st_q[4];
    #pragma unroll
    for (int c = 0; c < 4; ++c) {
        int slot = c * 256 + tid;
        int r = slot >> 3;
        st_r[c] = r;
        st_q[c] = ((slot & 7) ^ (r & 7)) * 16;   // byte offset
    }

    floatx4 acc[2][4][4] = {};

    for (int kt = 0; kt < KTOT / 128; ++kt) {
        const int kb = kt * 128;
        #pragma unroll
        for (int c = 0; c < 4; ++c) {
            async16(A + (size_t)min(row0 + st_r[c], Mm1) * KTOT + kb + st_q[c],
                    &As[0][(c * 256 + wave * 64) * 16]);
        }
        #pragma unroll
        for (int c = 0; c < 4; ++c) {
            async16(A + (size_t)min(row0 + 128 + st_r[c], Mm1) * KTOT + kb + st_q[c],
                    &As[1][(c * 256 + wave * 64) * 16]);
        }
        #pragma unroll
        for (int c = 0; c < 4; ++c) {
            async16(Bt + (size_t)(col0 + st_r[c]) * KTOT + kb + st_q[c],
                    &Bs[(c * 256 + wave * 64) * 16]);
        }
        __syncthreads();
        #pragma unroll
        for (int kk = 0; kk < 4; ++kk) {
            const int c0 = kk * 2 + (quad >> 1);
            const int o8 = (quad & 1) * 8;
            long b[4];
            #pragma unroll
            for (int t = 0; t < 4; ++t) {
                int r = n0w + t * 16 + l16;
                b[t] = *(const long*)&Bs[r * 128 + ((c0 ^ (r & 7)) * 16) + o8];
            }
            #pragma unroll
            for (int rt = 0; rt < 2; ++rt) {
                long a[4];
                #pragma unroll
                for (int t = 0; t < 4; ++t) {
                    int r = m0w + t * 16 + l16;
                    a[t] = *(const long*)&As[rt][r * 128 + ((c0 ^ (r & 7)) * 16) + o8];
                }
                #pragma unroll
                for (int i = 0; i < 4; ++i)
                    #pragma unroll
                    for (int j = 0; j < 4; ++j)
                        acc[rt][i][j] = __builtin_amdgcn_mfma_f32_16x16x32_fp8_fp8(a[i], b[j], acc[rt][i][j], 0, 0, 0);
            }
        }
        __syncthreads();
    }

    float bias4[4];
    #pragma unroll
    for (int j = 0; j < 4; ++j) bias4[j] = bias[col0 + n0w + j * 16 + l16];

    #pragma unroll
    for (int rt = 0; rt < 2; ++rt) {
        const int r0 = row0 + rt * 128;
        if (!POOL) {
            #pragma unroll
            for (int i = 0; i < 4; ++i) {
                #pragma unroll
                for (int r = 0; r < 4; ++r) {
                    int m = r0 + m0w + i * 16 + quad * 4 + r;
                    if (m < N_NODES) {
                        #pragma unroll
                        for (int j = 0; j < 4; ++j) {
                            float v = fmaxf(acc[rt][i][j][r] + bias4[j], 0.f);
                            outf8[(size_t)m * OUTSTR + col0 + n0w + j * 16 + l16] = f2f8(v);
                        }
                    }
                }
            }
        } else {
            if (rt) __syncthreads();    // protect pool2 reuse across subtiles
            if (r0 >= N_NODES) break;
            int gmin = batch[r0];
            int gmax = batch[min(r0 + 127, N_NODES - 1)];
            int span = gmax - gmin + 1;
            if (span == 1) {
                float s[4] = {0.f, 0.f, 0.f, 0.f};
                #pragma unroll
                for (int i = 0; i < 4; ++i) {
                    #pragma unroll
                    for (int r = 0; r < 4; ++r) {
                        int m = r0 + m0w + i * 16 + quad * 4 + r;
                        if (m < N_NODES) {
                            #pragma unroll
                            for (int j = 0; j < 4; ++j)
                                s[j] += fmaxf(acc[rt][i][j][r] + bias4[j], 0.f);
                        }
                    }
                }
                int slot = (wave & 1) * 4 + quad;
                #pragma unroll
                for (int j = 0; j < 4; ++j)
                    pool2[slot * 128 + n0w + j * 16 + l16] = s[j];
                __syncthreads();
                if (tid < 128) {
                    float v = 0.f;
                    #pragma unroll
                    for (int k = 0; k < 8; ++k) v += pool2[k * 128 + tid];
                    atomicAdd(psum + (size_t)gmin * HID + col0 + tid, v);
                }
            } else if (span <= 8) {
                for (int i = tid; i < span * 128; i += 256) pool2[i] = 0.f;
                __syncthreads();
                float s[4] = {0.f, 0.f, 0.f, 0.f};
                int cg = -1;
                #pragma unroll
                for (int i = 0; i < 4; ++i) {
                    #pragma unroll
                    for (int r = 0; r < 4; ++r) {
                        int m = r0 + m0w + i * 16 + quad * 4 + r;
                        if (m < N_NODES) {
                            int g = batch[m] - gmin;
                            if (g != cg) {
                                if (cg >= 0) {
                                    #pragma unroll
                                    for (int j = 0; j < 4; ++j)
                                        atomicAdd(&pool2[cg * 128 + n0w + j * 16 + l16], s[j]);
                                }
                                cg = g;
                                s[0] = s[1] = s[2] = s[3] = 0.f;
                            }
                            #pragma unroll
                            for (int j = 0; j < 4; ++j)
                                s[j] += fmaxf(acc[rt][i][j][r] + bias4[j], 0.f);
                        }
                    }
                }
                if (cg >= 0) {
                    #pragma unroll
                    for (int j = 0; j < 4; ++j)
                        atomicAdd(&pool2[cg * 128 + n0w + j * 16 + l16], s[j]);
                }
                __syncthreads();
                for (int i = tid; i < span * 128; i += 256) {
                    float v = pool2[i];
                    if (v != 0.f)
                        atomicAdd(psum + (size_t)(gmin + (i >> 7)) * HID + col0 + (i & 127), v);
                }
            } else {
                #pragma unroll
                for (int i = 0; i < 4; ++i) {
                    #pragma unroll
                    for (int r = 0; r < 4; ++r) {
                        int m = r0 + m0w + i * 16 + quad * 4 + r;
                        if (m < N_NODES) {
                            int g = batch[m];
                            #pragma unroll
                            for (int j = 0; j < 4; ++j) {
                                float v = fmaxf(acc[rt][i][j][r] + bias4[j], 0.f);
                                atomicAdd(psum + (size_t)g * HID + col0 + n0w + j * 16 + l16, v);
                            }
                        }
                    }
                }
            }
        }
    }
}

// ---------------- head: split-K hidden/cell partials ----------------
// grid (2, 64, KC), block 256: wave w handles col tile (blockIdx.x*4 + w)
__global__ __launch_bounds__(256) void head_hc_part(
    const float* __restrict__ psum, const float* __restrict__ Wh,
    const float* __restrict__ Wc, float* __restrict__ hpart,
    float* __restrict__ cpart)
{
    __shared__ float p[KCH];
    const int g = blockIdx.y, kc = blockIdx.z;
    const int k0 = kc * KCH;
    const int t = threadIdx.x;
    if (t < KCH) p[t] = psum[(size_t)g * HID + k0 + t];
    __syncthreads();
    const int tile = blockIdx.x * 4 + (t >> 6);
    const int col = tile * 64 + (t & 63);
    float h = 0.f, c = 0.f;
    #pragma unroll 8
    for (int k = 0; k < KCH; ++k) {
        float pk = p[k];
        h = fmaf(pk, Wh[(size_t)(k0 + k) * HID + col], h);
        c = fmaf(pk, Wc[(size_t)(k0 + k) * HID + col], c);
    }
    hpart[((size_t)kc * N_GRAPHS + g) * HID + col] = h;
    cpart[((size_t)kc * N_GRAPHS + g) * HID + col] = c;
}

// ---------------- head: reduce hc partials + bias + mean; logits K-chunk partials ----------------
// grid (KO, 64), block 512
__global__ __launch_bounds__(512) void head_out2_kernel(
    const float* __restrict__ hpart, const float* __restrict__ cpart,
    const int* __restrict__ batch,
    const float* __restrict__ bh, const float* __restrict__ bc,
    const float* __restrict__ Wout, float* __restrict__ lpart,
    float* __restrict__ out)
{
    __shared__ float hrow[HID];
    const int kc2 = blockIdx.x, g = blockIdx.y, j = threadIdx.x;

    // graph node count via binary search (uniform across threads)
    int lo = 0, hi = N_NODES;
    while (lo < hi) { int mid = (lo + hi) >> 1; if (batch[mid] < g) lo = mid + 1; else hi = mid; }
    int lo2 = lo, hi2 = N_NODES;
    while (lo2 < hi2) { int mid = (lo2 + hi2) >> 1; if (batch[mid] < g + 1) lo2 = mid + 1; else hi2 = mid; }
    float inv = 1.0f / fmaxf((float)(lo2 - lo), 1.0f);

    float hs = 0.f, cs = 0.f;
    #pragma unroll
    for (int kc = 0; kc < KC; ++kc) {
        hs += hpart[((size_t)kc * N_GRAPHS + g) * HID + j];
        cs += cpart[((size_t)kc * N_GRAPHS + g) * HID + j];
    }
    float hv = fmaf(hs, inv, bh[j]);
    hrow[j] = hv;
    if (kc2 == 0) {
        out[(size_t)N_GRAPHS * VOCAB + (size_t)g * HID + j] = hv;                      // hidden
        out[(size_t)2 * N_GRAPHS * VOCAB + (size_t)g * HID + j] = fmaf(cs, inv, bc[j]); // cell
    }
    __syncthreads();

    const int k0 = kc2 * KOH;
    float l = 0.f;
    #pragma unroll 8
    for (int k = 0; k < KOH; ++k)
        l = fmaf(hrow[k0 + k], Wout[(size_t)(k0 + k) * VOCAB + j], l);
    lpart[((size_t)kc2 * N_GRAPHS + g) * VOCAB + j] = l;
}

// ---------------- head: reduce logits partials + log_softmax ----------------
__global__ __launch_bounds__(512) void head_fin_kernel(
    const float* __restrict__ lpart, const float* __restrict__ bout,
    float* __restrict__ out)
{
    __shared__ float redm[8];
    __shared__ float reds[8];
    __shared__ float bm, bs;
    const int g = blockIdx.x, j = threadIdx.x;

    float l = bout[j];
    #pragma unroll
    for (int kc = 0; kc < KO; ++kc)
        l += lpart[((size_t)kc * N_GRAPHS + g) * VOCAB + j];

    const int lane = j & 63, wave = j >> 6;
    float m = l;
    #pragma unroll
    for (int o = 32; o > 0; o >>= 1) m = fmaxf(m, __shfl_down(m, o));
    if (lane == 0) redm[wave] = m;
    __syncthreads();
    if (j == 0) {
        float mm = redm[0];
        for (int w = 1; w < 8; ++w) mm = fmaxf(mm, redm[w]);
        bm = mm;
    }
    __syncthreads();
    m = bm;
    float e = __expf(l - m);
    float s = e;
    #pragma unroll
    for (int o = 32; o > 0; o >>= 1) s += __shfl_down(s, o);
    if (lane == 0) reds[wave] = s;
    __syncthreads();
    if (j == 0) {
        float ss = 0.f;
        for (int w = 0; w < 8; ++w) ss += reds[w];
        bs = ss;
    }
    __syncthreads();
    out[(size_t)g * VOCAB + j] = l - m - logf(bs);                  // logits
}

// ---------------- launch ----------------
extern "C" void kernel_launch(void* const* d_in, const int* in_sizes, int n_in,
                              void* d_out, int out_size, void* d_ws, size_t ws_size,
                              hipStream_t stream) {
    const float* x      = (const float*)d_in[1];
    const int*   edge   = (const int*)d_in[2];
    const int*   batch  = (const int*)d_in[3];
    const float* Wroot1 = (const float*)d_in[4];
    const float* Wrel1  = (const float*)d_in[5];
    const float* b1     = (const float*)d_in[6];
    const float* Wroot2 = (const float*)d_in[7];
    const float* Wrel2  = (const float*)d_in[8];
    const float* b2     = (const float*)d_in[9];
    const float* Wh     = (const float*)d_in[10];
    const float* bh     = (const float*)d_in[11];
    const float* Wc     = (const float*)d_in[12];
    const float* bc     = (const float*)d_in[13];
    const float* Wout   = (const float*)d_in[14];
    const float* bout   = (const float*)d_in[15];
    float* out = (float*)d_out;

    // workspace layout: bktcnt (padded) + psum first (single minimal memset)
    int*      bktcnt  = (int*)d_ws;                        // 128*16 ints (zeroed, 64B-strided counters)
    float*    psum    = (float*)(bktcnt + 128 * BC_STR);   // 64*512 (zeroed)
    int*      cnt     = (int*)(psum + N_GRAPHS * HID);     // 50000 (written by bucket_kernel)
    int*      srcbuf  = cnt + N_NODES;                     // 50000*64 padded CSR
    int2*     bktbuf  = (int2*)(srcbuf + (size_t)N_NODES * BKT);     // 98*10240 pairs (8.03MB)
    uchar_t*  xa8     = (uchar_t*)(bktbuf + (size_t)NPB * BCAP);     // 50000*256 fp8
    uchar_t*  w1t8    = xa8 + (size_t)N_NODES * 256;       // 256*256 fp8
    uchar_t*  h1a8    = w1t8 + 256 * 256;                  // 50000*512 fp8
    uchar_t*  w2t8    = h1a8 + (size_t)N_NODES * 512;      // 512*512 fp8
    float*    hpart   = (float*)(w2t8 + 512 * 512);        // KC*64*512 (512 KB)
    float*    cpart   = hpart + (size_t)KC * N_GRAPHS * HID;
    float*    lpart   = cpart + (size_t)KC * N_GRAPHS * HID;  // KO*64*512 (512 KB)

    hipMemsetAsync(d_ws, 0, (size_t)(128 * BC_STR + N_GRAPHS * HID) * 4, stream);

    prep_kernel<<<PA_BLOCKS + CONV_BLOCKS, 256, 0, stream>>>(
        edge, bktcnt, bktbuf, x, Wroot1, Wrel1, Wroot2, Wrel2, xa8, w1t8, w2t8);

    bucket_kernel<<<NPB, 512, 0, stream>>>(bktcnt, bktbuf, srcbuf, cnt);

    gather1_kernel<<<(N_NODES + 3) / 4, 256, 0, stream>>>(cnt, srcbuf, xa8);

    {   // layer 1: A=xa8 [50000 x 256] fp8, B=w1t8 fp8 -> h1a8 cols 0..255 fp8; COLS=2
        mfma_gemm_f8<256, 512, false, 2><<<8 * RPX2 * 2, 256, 0, stream>>>(
            xa8, w1t8, b1, h1a8, nullptr, nullptr);
    }

    gather2_kernel<<<(N_NODES + 3) / 4, 256, 0, stream>>>(cnt, srcbuf, h1a8);

    {   // layer 2: A=h1a8 [50000 x 512] fp8, B=w2t8 fp8 -> pooled psum; COLS=4
        mfma_gemm_f8<512, 0, true, 4><<<8 * RPX2 * 4, 256, 0, stream>>>(
            h1a8, w2t8, b2, nullptr, psum, batch);
    }

    head_hc_part<<<dim3(2, 64, KC), 256, 0, stream>>>(psum, Wh, Wc, hpart, cpart);
    head_out2_kernel<<<dim3(KO, 64), 512, 0, stream>>>(
        hpart, cpart, batch, bh, bc, Wout, lpart, out);
    head_fin_kernel<<<N_GRAPHS, 512, 0, stream>>>(lpart, bout, out);
}

// Round 11
// 271.532 us; speedup vs baseline: 1.0766x; 1.0766x over previous
//
#include <hip/hip_runtime.h>
#include <hip/hip_bf16.h>

#define N_NODES 50000
#define N_EDGES 800000
#define N_GRAPHS 64
#define FEAT 128
#define EMB 256
#define HID 512
#define VOCAB 512

#define RB ((N_NODES + 127) / 128)                  // 391 row-blocks
#define RPX ((RB + 7) / 8)                          // 49 row-blocks per XCD
#define BKT 64                                      // padded-CSR bucket width (deg ~Poisson(16), max ~38)

// ---- partition sort geometry ----
#define NPB 98                                      // coarse buckets: dst>>9 (512 nodes each)
#define BCAP 10240                                  // capacity per coarse bucket (mean 8163, +20 sigma safe)
#define PA_EDGES 4096                               // edges per phase-A block
#define PA_BLOCKS ((N_EDGES + PA_EDGES - 1) / PA_EDGES)  // 196
#define BC_STR 16                                   // bktcnt stride in ints (64B padding)

// ---- head split-K geometry ----
#define KC 4                                        // k-chunks for head_hc split
#define KCH (HID / KC)                              // 128 k per chunk
#define KO 4                                        // k-chunks for logits split
#define KOH (HID / KO)                              // 128 k per chunk

#define CONV_ELEMS (N_NODES * 32 + 256 * 256 + 512 * 512)  // 1,927,680
#define CONV_BLOCKS (CONV_ELEMS / 256)              // 7530

typedef __attribute__((ext_vector_type(4))) float floatx4;
typedef __attribute__((ext_vector_type(2))) float floatx2;
typedef unsigned int uint32;
typedef unsigned char uchar_t;

// u holds 4 fp8 e4m3; accumulate into a[0..3]
__device__ __forceinline__ void accf8(uint32 u, float* a) {
    floatx2 lo = __builtin_amdgcn_cvt_pk_f32_fp8(u, false);
    floatx2 hi = __builtin_amdgcn_cvt_pk_f32_fp8(u, true);
    a[0] += lo[0]; a[1] += lo[1]; a[2] += hi[0]; a[3] += hi[1];
}
__device__ __forceinline__ uchar_t f2f8(float v) {
    return (uchar_t)(__builtin_amdgcn_cvt_pk_fp8_f32(v, v, 0, false) & 0xff);
}
__device__ __forceinline__ uint32 pk4f8(float a, float b, float c, float d) {
    uint32 w = __builtin_amdgcn_cvt_pk_fp8_f32(a, b, 0, false);
    return __builtin_amdgcn_cvt_pk_fp8_f32(c, d, w, true);
}
__device__ __forceinline__ void async16(const void* g, void* l) {
    __builtin_amdgcn_global_load_lds(
        (const __attribute__((address_space(1))) void*)g,
        (__attribute__((address_space(3))) void*)l, 16, 0, 0);
}

// ---------------- prep: phase-A partition (LDS-binned, coalesced out) + fp8 converts ----------------
__global__ void prep_kernel(const int* __restrict__ edge, int* __restrict__ bktcnt,
                            int2* __restrict__ bktbuf,
                            const float* __restrict__ x,
                            const float* __restrict__ W01, const float* __restrict__ W11,
                            const float* __restrict__ W02, const float* __restrict__ W12,
                            uchar_t* __restrict__ xa8,
                            uchar_t* __restrict__ w1t8, uchar_t* __restrict__ w2t8) {
    if (blockIdx.x < PA_BLOCKS) {
        __shared__ int hist[NPB];
        __shared__ int excl[NPB];
        __shared__ int lpos[NPB];
        __shared__ int gbase[NPB];
        __shared__ int2 stage[PA_EDGES];
        const int t = threadIdx.x;
        const int e0 = blockIdx.x * PA_EDGES;
        const int ne = min(PA_EDGES, N_EDGES - e0);

        if (t < NPB) hist[t] = 0;
        __syncthreads();
        for (int s = t; s < ne; s += 256) {
            int d = edge[N_EDGES + e0 + s];
            atomicAdd(&hist[d >> 9], 1);
        }
        __syncthreads();
        if (t == 0) {
            int run = 0;
            for (int i = 0; i < NPB; ++i) { excl[i] = run; run += hist[i]; }
        }
        __syncthreads();
        if (t < NPB) {
            gbase[t] = atomicAdd(bktcnt + t * BC_STR, hist[t]);
            lpos[t] = excl[t];
        }
        __syncthreads();
        for (int s = t; s < ne; s += 256) {
            int src = edge[e0 + s];
            int d = edge[N_EDGES + e0 + s];
            int b = d >> 9;
            int lp = atomicAdd(&lpos[b], 1);
            stage[lp] = make_int2(src, d);
        }
        __syncthreads();
        for (int s = t; s < ne; s += 256) {
            int2 p = stage[s];
            int b = p.y >> 9;
            int g = gbase[b] + (s - excl[b]);
            if (g < BCAP) bktbuf[(size_t)b * BCAP + g] = p;
        }
    } else {
        int tid = (blockIdx.x - PA_BLOCKS) * 256 + threadIdx.x;
        if (tid < N_NODES * 32) {
            int row = tid >> 5, c = (tid & 31) * 4;
            float4 v = *(const float4*)(x + (size_t)row * FEAT + c);
            *(uint32*)(xa8 + (size_t)row * 256 + c) = pk4f8(v.x, v.y, v.z, v.w);
        } else if (tid < N_NODES * 32 + 256 * 256) {
            int t1 = tid - N_NODES * 32;
            int n = t1 >> 8, k = t1 & 255;
            float v = (k < 128) ? W01[(size_t)k * 256 + n] : W11[(size_t)(k - 128) * 256 + n];
            w1t8[t1] = f2f8(v);
        } else {
            int t2 = tid - N_NODES * 32 - 256 * 256;
            int n = t2 >> 9, k = t2 & 511;
            float v = (k < 256) ? W02[(size_t)k * 512 + n] : W12[(size_t)(k - 256) * 512 + n];
            w2t8[t2] = f2f8(v);
        }
    }
}

// ---------------- phase B: per-bucket L2-local CSR scatter + exact counts (512 thr) ----------------
__global__ __launch_bounds__(512) void bucket_kernel(const int* __restrict__ bktcnt,
                                                     const int2* __restrict__ bktbuf,
                                                     int* __restrict__ srcbuf,
                                                     int* __restrict__ cnt) {
    __shared__ int lcur[512];
    const int b = blockIdx.x;
    const int t = threadIdx.x;
    const int n0 = b << 9;
    const int nn = min(512, N_NODES - n0);
    const int ne = min(bktcnt[b * BC_STR], BCAP);

    lcur[t] = 0;
    __syncthreads();
    for (int s = t; s < ne; s += 512) {
        int2 p = bktbuf[(size_t)b * BCAP + s];
        int d = p.y & 511;
        int k = atomicAdd(&lcur[d], 1);
        if (k < BKT) srcbuf[((size_t)(n0 + d) << 6) + k] = p.x;
    }
    __syncthreads();
    if (t < nn) cnt[n0 + t] = lcur[t];
}

// ---------------- CSR gathers (padded buckets, stride 64) ----------------
// gather1: fp8 in/out on xa8[50000][256] (cols 0..127 = x fp8, 128..255 = agg1 fp8)
__global__ __launch_bounds__(256) void gather1_kernel(
    const int* __restrict__ cnt, const int* __restrict__ srcbuf,
    uchar_t* __restrict__ xa8)
{
    int node = blockIdx.x * 4 + (threadIdx.x >> 6);
    if (node >= N_NODES) return;
    int lane = threadIdx.x & 63;
    int grp = lane >> 3;
    int l8 = lane & 7;
    int c_ = cnt[node];
    float ri = 1.0f / (float)max(c_, 1);
    int beg = node << 6;
    int end = beg + min(c_, BKT);

    float a[16];
    #pragma unroll
    for (int k = 0; k < 16; ++k) a[k] = 0.f;

    int j = beg + grp;
    for (; j + 8 < end; j += 16) {
        int s0 = srcbuf[j];
        int s1 = srcbuf[j + 8];
        uint4 u0 = *(const uint4*)(xa8 + (size_t)s0 * 256 + l8 * 16);
        uint4 u1 = *(const uint4*)(xa8 + (size_t)s1 * 256 + l8 * 16);
        accf8(u0.x, a + 0); accf8(u0.y, a + 4); accf8(u0.z, a + 8); accf8(u0.w, a + 12);
        accf8(u1.x, a + 0); accf8(u1.y, a + 4); accf8(u1.z, a + 8); accf8(u1.w, a + 12);
    }
    for (; j < end; j += 8) {
        int s0 = srcbuf[j];
        uint4 u0 = *(const uint4*)(xa8 + (size_t)s0 * 256 + l8 * 16);
        accf8(u0.x, a + 0); accf8(u0.y, a + 4); accf8(u0.z, a + 8); accf8(u0.w, a + 12);
    }
    #pragma unroll
    for (int k = 0; k < 16; ++k) a[k] += __shfl_down(a[k], 32);
    #pragma unroll
    for (int k = 0; k < 16; ++k) a[k] += __shfl_down(a[k], 16);
    #pragma unroll
    for (int k = 0; k < 16; ++k) a[k] += __shfl_down(a[k], 8);
    if (grp == 0) {
        uint4 o;
        o.x = pk4f8(a[0] * ri,  a[1] * ri,  a[2] * ri,  a[3] * ri);
        o.y = pk4f8(a[4] * ri,  a[5] * ri,  a[6] * ri,  a[7] * ri);
        o.z = pk4f8(a[8] * ri,  a[9] * ri,  a[10] * ri, a[11] * ri);
        o.w = pk4f8(a[12] * ri, a[13] * ri, a[14] * ri, a[15] * ri);
        *(uint4*)(xa8 + (size_t)node * 256 + 128 + l8 * 16) = o;
    }
}

// gather2: fp8 in/out on h1a8[50000][512] (cols 0..255 = h1 fp8, 256..511 = agg2 fp8)
__global__ __launch_bounds__(256) void gather2_kernel(
    const int* __restrict__ cnt, const int* __restrict__ srcbuf,
    uchar_t* __restrict__ h1a8)
{
    int node = blockIdx.x * 4 + (threadIdx.x >> 6);
    if (node >= N_NODES) return;
    int lane = threadIdx.x & 63;
    int grp = lane >> 4;
    int l16 = lane & 15;
    int c_ = cnt[node];
    float ri = 1.0f / (float)max(c_, 1);
    int beg = node << 6;
    int end = beg + min(c_, BKT);

    float a[16];
    #pragma unroll
    for (int k = 0; k < 16; ++k) a[k] = 0.f;

    int j = beg + grp;
    for (; j + 4 < end; j += 8) {
        int s0 = srcbuf[j];
        int s1 = srcbuf[j + 4];
        uint4 u0 = *(const uint4*)(h1a8 + (size_t)s0 * 512 + l16 * 16);
        uint4 u1 = *(const uint4*)(h1a8 + (size_t)s1 * 512 + l16 * 16);
        accf8(u0.x, a + 0); accf8(u0.y, a + 4); accf8(u0.z, a + 8); accf8(u0.w, a + 12);
        accf8(u1.x, a + 0); accf8(u1.y, a + 4); accf8(u1.z, a + 8); accf8(u1.w, a + 12);
    }
    for (; j < end; j += 4) {
        int s0 = srcbuf[j];
        uint4 u0 = *(const uint4*)(h1a8 + (size_t)s0 * 512 + l16 * 16);
        accf8(u0.x, a + 0); accf8(u0.y, a + 4); accf8(u0.z, a + 8); accf8(u0.w, a + 12);
    }
    #pragma unroll
    for (int k = 0; k < 16; ++k) a[k] += __shfl_down(a[k], 32);
    #pragma unroll
    for (int k = 0; k < 16; ++k) a[k] += __shfl_down(a[k], 16);
    if (grp == 0) {
        uint4 o;
        o.x = pk4f8(a[0] * ri,  a[1] * ri,  a[2] * ri,  a[3] * ri);
        o.y = pk4f8(a[4] * ri,  a[5] * ri,  a[6] * ri,  a[7] * ri);
        o.z = pk4f8(a[8] * ri,  a[9] * ri,  a[10] * ri, a[11] * ri);
        o.w = pk4f8(a[12] * ri, a[13] * ri, a[14] * ri, a[15] * ri);
        *(uint4*)(h1a8 + (size_t)node * 512 + 256 + l16 * 16) = o;
    }
}

// ---------------- fp8 MFMA GEMM (128x128 tile, BK=128 fp8, XCD-swizzled) ----------------
// POOL=false: relu(acc+bias) -> fp8 to outf8 (row stride OUTSTR) at col0.
// POOL=true : pool rows by batch[] into psum.
template<int KTOT, int OUTSTR, bool POOL, int COLS>
__global__ __launch_bounds__(256) void mfma_gemm_f8(
    const uchar_t* __restrict__ A, const uchar_t* __restrict__ Bt,
    const float* __restrict__ bias, uchar_t* __restrict__ outf8,
    float* __restrict__ psum, const int* __restrict__ batch)
{
    __shared__ uchar_t As[16384];       // 128 rows x 128 B (BK=128)
    __shared__ uchar_t Bs[16384];
    __shared__ float pool2[8 * 128];

    const int id = blockIdx.x;
    const int xcd = id & 7;
    const int s_ = id >> 3;
    const int col = s_ & (COLS - 1);
    const int rloc = s_ / COLS;
    const int rowblk = xcd * RPX + rloc;
    if (rowblk >= RB) return;

    const int tid = threadIdx.x;
    const int lane = tid & 63;
    const int wave = tid >> 6;
    const int quad = lane >> 4;
    const int l16 = lane & 15;
    const int m0w = (wave & 1) * 64;
    const int n0w = (wave >> 1) * 64;
    const int row0 = rowblk * 128;
    const int col0 = col * 128;
    const int Mm1 = N_NODES - 1;

    int st_r[4], st_q[4];
    #pragma unroll
    for (int c = 0; c < 4; ++c) {
        int slot = c * 256 + tid;
        int r = slot >> 3;
        st_r[c] = r;
        st_q[c] = ((slot & 7) ^ (r & 7)) * 16;   // byte offset
    }

    floatx4 acc[4][4] = {};

    for (int kt = 0; kt < KTOT / 128; ++kt) {
        const int kb = kt * 128;
        #pragma unroll
        for (int c = 0; c < 4; ++c) {
            async16(A + (size_t)min(row0 + st_r[c], Mm1) * KTOT + kb + st_q[c],
                    &As[(c * 256 + wave * 64) * 16]);
        }
        #pragma unroll
        for (int c = 0; c < 4; ++c) {
            async16(Bt + (size_t)(col0 + st_r[c]) * KTOT + kb + st_q[c],
                    &Bs[(c * 256 + wave * 64) * 16]);
        }
        __syncthreads();
        #pragma unroll
        for (int kk = 0; kk < 4; ++kk) {
            const int c0 = kk * 2 + (quad >> 1);
            const int o8 = (quad & 1) * 8;
            long a[4], b[4];
            #pragma unroll
            for (int t = 0; t < 4; ++t) {
                int r = m0w + t * 16 + l16;
                a[t] = *(const long*)&As[r * 128 + ((c0 ^ (r & 7)) * 16) + o8];
            }
            #pragma unroll
            for (int t = 0; t < 4; ++t) {
                int r = n0w + t * 16 + l16;
                b[t] = *(const long*)&Bs[r * 128 + ((c0 ^ (r & 7)) * 16) + o8];
            }
            #pragma unroll
            for (int i = 0; i < 4; ++i)
                #pragma unroll
                for (int j = 0; j < 4; ++j)
                    acc[i][j] = __builtin_amdgcn_mfma_f32_16x16x32_fp8_fp8(a[i], b[j], acc[i][j], 0, 0, 0);
        }
        __syncthreads();
    }

    float bias4[4];
    #pragma unroll
    for (int j = 0; j < 4; ++j) bias4[j] = bias[col0 + n0w + j * 16 + l16];

    if (!POOL) {
        #pragma unroll
        for (int i = 0; i < 4; ++i) {
            #pragma unroll
            for (int r = 0; r < 4; ++r) {
                int m = row0 + m0w + i * 16 + quad * 4 + r;
                if (m < N_NODES) {
                    #pragma unroll
                    for (int j = 0; j < 4; ++j) {
                        float v = fmaxf(acc[i][j][r] + bias4[j], 0.f);
                        outf8[(size_t)m * OUTSTR + col0 + n0w + j * 16 + l16] = f2f8(v);
                    }
                }
            }
        }
    } else {
        int gmin = batch[row0];
        int gmax = batch[min(row0 + 127, N_NODES - 1)];
        int span = gmax - gmin + 1;
        if (span == 1) {
            float s[4] = {0.f, 0.f, 0.f, 0.f};
            #pragma unroll
            for (int i = 0; i < 4; ++i) {
                #pragma unroll
                for (int r = 0; r < 4; ++r) {
                    int m = row0 + m0w + i * 16 + quad * 4 + r;
                    if (m < N_NODES) {
                        #pragma unroll
                        for (int j = 0; j < 4; ++j)
                            s[j] += fmaxf(acc[i][j][r] + bias4[j], 0.f);
                    }
                }
            }
            int slot = (wave & 1) * 4 + quad;
            #pragma unroll
            for (int j = 0; j < 4; ++j)
                pool2[slot * 128 + n0w + j * 16 + l16] = s[j];
            __syncthreads();
            if (tid < 128) {
                float v = 0.f;
                #pragma unroll
                for (int k = 0; k < 8; ++k) v += pool2[k * 128 + tid];
                atomicAdd(psum + (size_t)gmin * HID + col0 + tid, v);
            }
        } else if (span <= 8) {
            for (int i = tid; i < span * 128; i += 256) pool2[i] = 0.f;
            __syncthreads();
            float s[4] = {0.f, 0.f, 0.f, 0.f};
            int cg = -1;
            #pragma unroll
            for (int i = 0; i < 4; ++i) {
                #pragma unroll
                for (int r = 0; r < 4; ++r) {
                    int m = row0 + m0w + i * 16 + quad * 4 + r;
                    if (m < N_NODES) {
                        int g = batch[m] - gmin;
                        if (g != cg) {
                            if (cg >= 0) {
                                #pragma unroll
                                for (int j = 0; j < 4; ++j)
                                    atomicAdd(&pool2[cg * 128 + n0w + j * 16 + l16], s[j]);
                            }
                            cg = g;
                            s[0] = s[1] = s[2] = s[3] = 0.f;
                        }
                        #pragma unroll
                        for (int j = 0; j < 4; ++j)
                            s[j] += fmaxf(acc[i][j][r] + bias4[j], 0.f);
                    }
                }
            }
            if (cg >= 0) {
                #pragma unroll
                for (int j = 0; j < 4; ++j)
                    atomicAdd(&pool2[cg * 128 + n0w + j * 16 + l16], s[j]);
            }
            __syncthreads();
            for (int i = tid; i < span * 128; i += 256) {
                float v = pool2[i];
                if (v != 0.f)
                    atomicAdd(psum + (size_t)(gmin + (i >> 7)) * HID + col0 + (i & 127), v);
            }
        } else {
            #pragma unroll
            for (int i = 0; i < 4; ++i) {
                #pragma unroll
                for (int r = 0; r < 4; ++r) {
                    int m = row0 + m0w + i * 16 + quad * 4 + r;
                    if (m < N_NODES) {
                        int g = batch[m];
                        #pragma unroll
                        for (int j = 0; j < 4; ++j) {
                            float v = fmaxf(acc[i][j][r] + bias4[j], 0.f);
                            atomicAdd(psum + (size_t)g * HID + col0 + n0w + j * 16 + l16, v);
                        }
                    }
                }
            }
        }
    }
}

// ---------------- head: split-K hidden/cell partials ----------------
// grid (2, 64, KC), block 256: wave w handles col tile (blockIdx.x*4 + w)
__global__ __launch_bounds__(256) void head_hc_part(
    const float* __restrict__ psum, const float* __restrict__ Wh,
    const float* __restrict__ Wc, float* __restrict__ hpart,
    float* __restrict__ cpart)
{
    __shared__ float p[KCH];
    const int g = blockIdx.y, kc = blockIdx.z;
    const int k0 = kc * KCH;
    const int t = threadIdx.x;
    if (t < KCH) p[t] = psum[(size_t)g * HID + k0 + t];
    __syncthreads();
    const int tile = blockIdx.x * 4 + (t >> 6);
    const int col = tile * 64 + (t & 63);
    float h = 0.f, c = 0.f;
    #pragma unroll 8
    for (int k = 0; k < KCH; ++k) {
        float pk = p[k];
        h = fmaf(pk, Wh[(size_t)(k0 + k) * HID + col], h);
        c = fmaf(pk, Wc[(size_t)(k0 + k) * HID + col], c);
    }
    hpart[((size_t)kc * N_GRAPHS + g) * HID + col] = h;
    cpart[((size_t)kc * N_GRAPHS + g) * HID + col] = c;
}

// ---------------- head: reduce hc partials + bias + mean; logits K-chunk partials ----------------
// grid (KO, 64), block 512
__global__ __launch_bounds__(512) void head_out2_kernel(
    const float* __restrict__ hpart, const float* __restrict__ cpart,
    const int* __restrict__ batch,
    const float* __restrict__ bh, const float* __restrict__ bc,
    const float* __restrict__ Wout, float* __restrict__ lpart,
    float* __restrict__ out)
{
    __shared__ float hrow[HID];
    const int kc2 = blockIdx.x, g = blockIdx.y, j = threadIdx.x;

    // graph node count via binary search (uniform across threads)
    int lo = 0, hi = N_NODES;
    while (lo < hi) { int mid = (lo + hi) >> 1; if (batch[mid] < g) lo = mid + 1; else hi = mid; }
    int lo2 = lo, hi2 = N_NODES;
    while (lo2 < hi2) { int mid = (lo2 + hi2) >> 1; if (batch[mid] < g + 1) lo2 = mid + 1; else hi2 = mid; }
    float inv = 1.0f / fmaxf((float)(lo2 - lo), 1.0f);

    float hs = 0.f, cs = 0.f;
    #pragma unroll
    for (int kc = 0; kc < KC; ++kc) {
        hs += hpart[((size_t)kc * N_GRAPHS + g) * HID + j];
        cs += cpart[((size_t)kc * N_GRAPHS + g) * HID + j];
    }
    float hv = fmaf(hs, inv, bh[j]);
    hrow[j] = hv;
    if (kc2 == 0) {
        out[(size_t)N_GRAPHS * VOCAB + (size_t)g * HID + j] = hv;                      // hidden
        out[(size_t)2 * N_GRAPHS * VOCAB + (size_t)g * HID + j] = fmaf(cs, inv, bc[j]); // cell
    }
    __syncthreads();

    const int k0 = kc2 * KOH;
    float l = 0.f;
    #pragma unroll 8
    for (int k = 0; k < KOH; ++k)
        l = fmaf(hrow[k0 + k], Wout[(size_t)(k0 + k) * VOCAB + j], l);
    lpart[((size_t)kc2 * N_GRAPHS + g) * VOCAB + j] = l;
}

// ---------------- head: reduce logits partials + log_softmax ----------------
__global__ __launch_bounds__(512) void head_fin_kernel(
    const float* __restrict__ lpart, const float* __restrict__ bout,
    float* __restrict__ out)
{
    __shared__ float redm[8];
    __shared__ float reds[8];
    __shared__ float bm, bs;
    const int g = blockIdx.x, j = threadIdx.x;

    float l = bout[j];
    #pragma unroll
    for (int kc = 0; kc < KO; ++kc)
        l += lpart[((size_t)kc * N_GRAPHS + g) * VOCAB + j];

    const int lane = j & 63, wave = j >> 6;
    float m = l;
    #pragma unroll
    for (int o = 32; o > 0; o >>= 1) m = fmaxf(m, __shfl_down(m, o));
    if (lane == 0) redm[wave] = m;
    __syncthreads();
    if (j == 0) {
        float mm = redm[0];
        for (int w = 1; w < 8; ++w) mm = fmaxf(mm, redm[w]);
        bm = mm;
    }
    __syncthreads();
    m = bm;
    float e = __expf(l - m);
    float s = e;
    #pragma unroll
    for (int o = 32; o > 0; o >>= 1) s += __shfl_down(s, o);
    if (lane == 0) reds[wave] = s;
    __syncthreads();
    if (j == 0) {
        float ss = 0.f;
        for (int w = 0; w < 8; ++w) ss += reds[w];
        bs = ss;
    }
    __syncthreads();
    out[(size_t)g * VOCAB + j] = l - m - logf(bs);                  // logits
}

// ---------------- launch ----------------
extern "C" void kernel_launch(void* const* d_in, const int* in_sizes, int n_in,
                              void* d_out, int out_size, void* d_ws, size_t ws_size,
                              hipStream_t stream) {
    const float* x      = (const float*)d_in[1];
    const int*   edge   = (const int*)d_in[2];
    const int*   batch  = (const int*)d_in[3];
    const float* Wroot1 = (const float*)d_in[4];
    const float* Wrel1  = (const float*)d_in[5];
    const float* b1     = (const float*)d_in[6];
    const float* Wroot2 = (const float*)d_in[7];
    const float* Wrel2  = (const float*)d_in[8];
    const float* b2     = (const float*)d_in[9];
    const float* Wh     = (const float*)d_in[10];
    const float* bh     = (const float*)d_in[11];
    const float* Wc     = (const float*)d_in[12];
    const float* bc     = (const float*)d_in[13];
    const float* Wout   = (const float*)d_in[14];
    const float* bout   = (const float*)d_in[15];
    float* out = (float*)d_out;

    // workspace layout: bktcnt (padded) + psum first (single minimal memset)
    int*      bktcnt  = (int*)d_ws;                        // 128*16 ints (zeroed, 64B-strided counters)
    float*    psum    = (float*)(bktcnt + 128 * BC_STR);   // 64*512 (zeroed)
    int*      cnt     = (int*)(psum + N_GRAPHS * HID);     // 50000 (written by bucket_kernel)
    int*      srcbuf  = cnt + N_NODES;                     // 50000*64 padded CSR
    int2*     bktbuf  = (int2*)(srcbuf + (size_t)N_NODES * BKT);     // 98*10240 pairs (8.03MB)
    uchar_t*  xa8     = (uchar_t*)(bktbuf + (size_t)NPB * BCAP);     // 50000*256 fp8
    uchar_t*  w1t8    = xa8 + (size_t)N_NODES * 256;       // 256*256 fp8
    uchar_t*  h1a8    = w1t8 + 256 * 256;                  // 50000*512 fp8
    uchar_t*  w2t8    = h1a8 + (size_t)N_NODES * 512;      // 512*512 fp8
    float*    hpart   = (float*)(w2t8 + 512 * 512);        // KC*64*512 (512 KB)
    float*    cpart   = hpart + (size_t)KC * N_GRAPHS * HID;
    float*    lpart   = cpart + (size_t)KC * N_GRAPHS * HID;  // KO*64*512 (512 KB)

    hipMemsetAsync(d_ws, 0, (size_t)(128 * BC_STR + N_GRAPHS * HID) * 4, stream);

    prep_kernel<<<PA_BLOCKS + CONV_BLOCKS, 256, 0, stream>>>(
        edge, bktcnt, bktbuf, x, Wroot1, Wrel1, Wroot2, Wrel2, xa8, w1t8, w2t8);

    bucket_kernel<<<NPB, 512, 0, stream>>>(bktcnt, bktbuf, srcbuf, cnt);

    gather1_kernel<<<(N_NODES + 3) / 4, 256, 0, stream>>>(cnt, srcbuf, xa8);

    {   // layer 1: A=xa8 [50000 x 256] fp8, B=w1t8 fp8 -> h1a8 cols 0..255 fp8; COLS=2
        mfma_gemm_f8<256, 512, false, 2><<<8 * RPX * 2, 256, 0, stream>>>(
            xa8, w1t8, b1, h1a8, nullptr, nullptr);
    }

    gather2_kernel<<<(N_NODES + 3) / 4, 256, 0, stream>>>(cnt, srcbuf, h1a8);

    {   // layer 2: A=h1a8 [50000 x 512] fp8, B=w2t8 fp8 -> pooled psum; COLS=4
        mfma_gemm_f8<512, 0, true, 4><<<8 * RPX * 4, 256, 0, stream>>>(
            h1a8, w2t8, b2, nullptr, psum, batch);
    }

    head_hc_part<<<dim3(2, 64, KC), 256, 0, stream>>>(psum, Wh, Wc, hpart, cpart);
    head_out2_kernel<<<dim3(KO, 64), 512, 0, stream>>>(
        hpart, cpart, batch, bh, bc, Wout, lpart, out);
    head_fin_kernel<<<N_GRAPHS, 512, 0, stream>>>(lpart, bout, out);
}